// Round 5
// baseline (366.060 us; speedup 1.0000x reference)
//
#include <hip/hip_runtime.h>

// SoftTriple loss, MI355X. B=256, E=512, C=8192, K=10.
// Persistent fused kernel: 256 blocks x 8 groups x 4 classes; fc streamed
// into double-buffered Wt while K-loop runs; Es (emb slices) double-buffered.
// ws layout (bytes):
//   [0, 262144)          embb bf16 [256][512]
//   [262144, 8650752)    hT float [8192][256]
//   [8650752, 8658944)   gram_part float[2048]
//   [8658944, 8790016)   part_m float[128][256]
//   [8790016, 8921088)   part_s float[128][256]

typedef __bf16 bf16;
typedef bf16 bf16x8 __attribute__((ext_vector_type(8)));
typedef bf16 bf16x4 __attribute__((ext_vector_type(4)));
typedef float f32x4 __attribute__((ext_vector_type(4)));

#define NCLASS 8192
#define KC 10
#define EDIM 512
#define BATCH 256
#define CPB 4
#define GROUPS 8
#define WST 520                 // Wt row stride (bf16)
#define WTSZ (CPB * KC * WST)   // 20800 bf16 = 41600 B

__device__ inline void load_lds16(const void* g, void* l) {
    __builtin_amdgcn_global_load_lds(
        (const __attribute__((address_space(1))) void*)g,
        (__attribute__((address_space(3))) void*)l, 16, 0, 0);
}

// ---------------- kernel 1: embeddings fp32 -> bf16 -----------------------
__global__ __launch_bounds__(256) void conv_kernel(
    const float* __restrict__ e, bf16* __restrict__ out)
{
    int i = blockIdx.x * 256 + threadIdx.x;   // 64 blocks * 256 * 8 = 131072
    float4 a = ((const float4*)e)[i * 2];
    float4 b = ((const float4*)e)[i * 2 + 1];
    bf16x8 v;
    v[0] = (bf16)a.x; v[1] = (bf16)a.y; v[2] = (bf16)a.z; v[3] = (bf16)a.w;
    v[4] = (bf16)b.x; v[5] = (bf16)b.y; v[6] = (bf16)b.z; v[7] = (bf16)b.w;
    ((bf16x8*)out)[i] = v;
}

// ---------------- kernel 2: persistent fused --------------------------------
__global__ __launch_bounds__(512, 2) void fused_kernel(
    const float* __restrict__ fc, const bf16* __restrict__ embb,
    float* __restrict__ hT, float* __restrict__ gram_part)
{
    __shared__ bf16 Wt[2][WTSZ];            // 83200 B, double-buffered
    __shared__ bf16 Es[2][2][256 * 32];     // 65536 B, double-buffered BK=64
    __shared__ float s_invn[CPB * 16];
    __shared__ float s_part[2];

    const int t = threadIdx.x;
    const int wave = t >> 6, lane = t & 63;
    const int wm = wave >> 2, wn = wave & 3;   // 2 class-halves x 4 batch-slices
    const int m16 = lane & 15, quad = lane >> 4;
    const int clamp_m = (m16 < KC) ? m16 : 0;
    const int lrow = lane >> 2, lcol = (lane & 3) * 8;
    const long cbase = (long)blockIdx.x * (CPB * GROUPS);

    // prologue: phase A for group 0 -> Wt[0]
    {
        const float4* src = (const float4*)(fc + (size_t)cbase * (KC * EDIM));
        #pragma unroll
        for (int p = 0; p < 10; ++p) {
            int idx = t + p * 512;           // 5120 float4 = 40 rows x 128
            float4 v = src[idx];
            int row = idx >> 7, col = idx & 127;
            bf16x4 bv;
            bv[0] = (bf16)v.x; bv[1] = (bf16)v.y;
            bv[2] = (bf16)v.z; bv[3] = (bf16)v.w;
            *(bf16x4*)&Wt[0][row * WST + col * 4] = bv;
        }
    }
    // stage Es buf0 with kb=0 slice
    #pragma unroll
    for (int h = 0; h < 2; ++h)
        #pragma unroll
        for (int p = 0; p < 2; ++p) {
            int r0 = wave * 32 + p * 16;
            load_lds16(embb + (size_t)(r0 + lrow) * EDIM + h * 32 + lcol,
                       &Es[0][h][r0 * 32]);
        }

    #pragma unroll 1
    for (int g = 0; g < GROUPS; ++g) {
        const int cur = g & 1;
        float4 pf[10];

        f32x4 acc[2][4], grm[2];
        #pragma unroll
        for (int mtl = 0; mtl < 2; ++mtl) {
            grm[mtl] = (f32x4){0.f, 0.f, 0.f, 0.f};
            #pragma unroll
            for (int nt = 0; nt < 4; ++nt)
                acc[mtl][nt] = (f32x4){0.f, 0.f, 0.f, 0.f};
        }

        int ebuf = 0;
        #pragma unroll
        for (int kb = 0; kb < 8; ++kb) {
            __syncthreads();    // Es[ebuf](kb) ready; Wt[cur] ready
            // stage next Es slice into the other buffer (kb7 restages kb0)
            {
                int nkb = (kb + 1) & 7;
                #pragma unroll
                for (int h = 0; h < 2; ++h)
                    #pragma unroll
                    for (int p = 0; p < 2; ++p) {
                        int r0 = wave * 32 + p * 16;
                        load_lds16(embb + (size_t)(r0 + lrow) * EDIM
                                       + nkb * 64 + h * 32 + lcol,
                                   &Es[ebuf ^ 1][h][r0 * 32]);
                    }
            }
            // issue next group's fc loads early (drained at kb=1 barrier)
            if (kb == 0 && g + 1 < GROUPS) {
                const float4* src = (const float4*)
                    (fc + (size_t)(cbase + (g + 1) * CPB) * (KC * EDIM));
                #pragma unroll
                for (int p = 0; p < 10; ++p) pf[p] = src[t + p * 512];
            }

            bf16x8 wf[2][2], ef[2][4];
            #pragma unroll
            for (int h = 0; h < 2; ++h) {
                #pragma unroll
                for (int mtl = 0; mtl < 2; ++mtl)
                    wf[h][mtl] = *(const bf16x8*)
                        &Wt[cur][((wm * 2 + mtl) * KC + clamp_m) * WST
                                 + kb * 64 + h * 32 + quad * 8];
                #pragma unroll
                for (int nt = 0; nt < 4; ++nt)
                    ef[h][nt] = *(const bf16x8*)
                        &Es[ebuf][h][(wn * 64 + nt * 16 + m16) * 32 + quad * 8];
            }
            #pragma unroll
            for (int mtl = 0; mtl < 2; ++mtl)
                #pragma unroll
                for (int nt = 0; nt < 4; ++nt) {
                    acc[mtl][nt] = __builtin_amdgcn_mfma_f32_16x16x32_bf16(
                        wf[0][mtl], ef[0][nt], acc[mtl][nt], 0, 0, 0);
                    acc[mtl][nt] = __builtin_amdgcn_mfma_f32_16x16x32_bf16(
                        wf[1][mtl], ef[1][nt], acc[mtl][nt], 0, 0, 0);
                }
            if (wn == 0) {
                #pragma unroll
                for (int mtl = 0; mtl < 2; ++mtl) {
                    grm[mtl] = __builtin_amdgcn_mfma_f32_16x16x32_bf16(
                        wf[0][mtl], wf[0][mtl], grm[mtl], 0, 0, 0);
                    grm[mtl] = __builtin_amdgcn_mfma_f32_16x16x32_bf16(
                        wf[1][mtl], wf[1][mtl], grm[mtl], 0, 0, 0);
                }
            }
            ebuf ^= 1;
        }

        // store next group's Wt (other buffer; reads of it start next group)
        if (g + 1 < GROUPS) {
            #pragma unroll
            for (int p = 0; p < 10; ++p) {
                int idx = t + p * 512;
                int row = idx >> 7, col = idx & 127;
                bf16x4 bv;
                bv[0] = (bf16)pf[p].x; bv[1] = (bf16)pf[p].y;
                bv[2] = (bf16)pf[p].z; bv[3] = (bf16)pf[p].w;
                *(bf16x4*)&Wt[cur ^ 1][row * WST + col * 4] = bv;
            }
        }

        // gram -> s_invn + strict-upper partial (wn==0 waves; wm -> classes)
        if (wn == 0) {
            #pragma unroll
            for (int mtl = 0; mtl < 2; ++mtl) {
                int cl = wm * 2 + mtl;
                #pragma unroll
                for (int r = 0; r < 4; ++r)
                    if (quad * 4 + r == m16 && m16 < KC)
                        s_invn[cl * 16 + m16] =
                            1.0f / fmaxf(sqrtf(grm[mtl][r]), 1e-12f);
                if (lane >= KC && lane < 16) s_invn[cl * 16 + lane] = 0.f;
            }
            float part = 0.f;
            #pragma unroll
            for (int mtl = 0; mtl < 2; ++mtl) {
                int cl = wm * 2 + mtl;
                #pragma unroll
                for (int r = 0; r < 4; ++r) {
                    int row = quad * 4 + r, col = m16;
                    if (row < col && col < KC) {
                        float sub = 1.0f - grm[mtl][r]
                            * s_invn[cl * 16 + row] * s_invn[cl * 16 + col];
                        if (sub <= 0.f) sub = 1e-10f;
                        part += sqrtf(2.0f * sub);
                    }
                }
            }
            #pragma unroll
            for (int off = 32; off; off >>= 1) part += __shfl_xor(part, off);
            if (lane == 0) s_part[wm] = part;
        }
        __syncthreads();   // s_invn/s_part visible to all

        // epilogue: scale by invn, k-softmax, write hT
        #pragma unroll
        for (int mtl = 0; mtl < 2; ++mtl) {
            int cl = wm * 2 + mtl;
            long cls = cbase + g * CPB + cl;
            float4 iv = *(const float4*)&s_invn[cl * 16 + quad * 4];
            #pragma unroll
            for (int nt = 0; nt < 4; ++nt) {
                float x[4];
                float xm = -1e30f;
                #pragma unroll
                for (int r = 0; r < 4; ++r) {
                    x[r] = acc[mtl][nt][r] * ((const float*)&iv)[r];
                    if (quad * 4 + r < KC) xm = fmaxf(xm, x[r]);
                }
                xm = fmaxf(xm, __shfl_xor(xm, 16));
                xm = fmaxf(xm, __shfl_xor(xm, 32));
                float s1 = 0.f, s2 = 0.f;
                #pragma unroll
                for (int r = 0; r < 4; ++r) {
                    if (quad * 4 + r < KC) {
                        float e = __expf(10.0f * (x[r] - xm));
                        s1 += e; s2 += e * x[r];
                    }
                }
                s1 += __shfl_xor(s1, 16); s1 += __shfl_xor(s1, 32);
                s2 += __shfl_xor(s2, 16); s2 += __shfl_xor(s2, 32);
                if (quad == 0)
                    hT[cls * BATCH + wn * 64 + nt * 16 + m16] = s2 / s1;
            }
        }
        if (t == 0) gram_part[blockIdx.x * GROUPS + g] = s_part[0] + s_part[1];
        __syncthreads();   // protect s_invn/s_part rewrite next group
    }
}

// ---------------- kernel 3: CE slices, 4 independent online states --------
__global__ __launch_bounds__(256) void ce_kernel(
    const float* __restrict__ hT, const int* __restrict__ labels,
    float* __restrict__ part_m, float* __restrict__ part_s)
{
    const int s = blockIdx.x, b = threadIdx.x;   // 128 blocks x 64 classes
    const int lbl = labels[b];
    const int c0 = s * 64;
    float m[4] = {-1e30f, -1e30f, -1e30f, -1e30f};
    float sum[4] = {0.f, 0.f, 0.f, 0.f};
    #pragma unroll
    for (int i = 0; i < 16; ++i) {
        #pragma unroll
        for (int u = 0; u < 4; ++u) {
            int c = c0 + i * 4 + u;
            float x = 10.0f * hT[(size_t)c * BATCH + b];
            if (c == lbl) x -= 0.1f;             // LMD * MARGIN
            if (x > m[u]) { sum[u] = sum[u] * __expf(m[u] - x) + 1.0f; m[u] = x; }
            else sum[u] += __expf(x - m[u]);
        }
    }
    float M = m[0], S = sum[0];
    #pragma unroll
    for (int u = 1; u < 4; ++u) {
        if (m[u] > M) { S = S * __expf(M - m[u]) + sum[u]; M = m[u]; }
        else S += sum[u] * __expf(m[u] - M);
    }
    part_m[s * BATCH + b] = M;
    part_s[s * BATCH + b] = S;
}

// ---------------- kernel 4: merge slices + gram reduce + combine ----------
__global__ __launch_bounds__(256) void final_kernel(
    const float* __restrict__ part_m, const float* __restrict__ part_s,
    const float* __restrict__ hT, const int* __restrict__ labels,
    const float* __restrict__ gram_part, float* __restrict__ out)
{
    __shared__ float red[4];
    const int t = threadIdx.x, wave = t >> 6, lane = t & 63;
    float M[4] = {-1e30f, -1e30f, -1e30f, -1e30f};
    float S[4] = {0.f, 0.f, 0.f, 0.f};
    #pragma unroll
    for (int i = 0; i < 32; ++i) {
        #pragma unroll
        for (int u = 0; u < 4; ++u) {
            int s = u * 32 + i;
            float mm = part_m[s * BATCH + t], ss = part_s[s * BATCH + t];
            if (mm > M[u]) { S[u] = S[u] * __expf(M[u] - mm) + ss; M[u] = mm; }
            else S[u] += ss * __expf(mm - M[u]);
        }
    }
    float Mf = M[0], Sf = S[0];
    #pragma unroll
    for (int u = 1; u < 4; ++u) {
        if (M[u] > Mf) { Sf = Sf * __expf(Mf - M[u]) + S[u]; Mf = M[u]; }
        else Sf += S[u] * __expf(M[u] - Mf);
    }
    int lbl = labels[t];
    float xl = 10.0f * hT[(size_t)lbl * BATCH + t] - 0.1f;
    float ce = Mf + logf(Sf) - xl;               // -logp[label]
    float g = 0.f;
    #pragma unroll
    for (int i = 0; i < 8; ++i) g += gram_part[t + i * 256];
    float val = ce * (1.0f / 256.0f) + g * (0.2f / 737280.0f);  // C*K*(K-1)
    #pragma unroll
    for (int off = 32; off; off >>= 1) val += __shfl_xor(val, off);
    if (lane == 0) red[wave] = val;
    __syncthreads();
    if (t == 0) out[0] = red[0] + red[1] + red[2] + red[3];
}

extern "C" void kernel_launch(void* const* d_in, const int* in_sizes, int n_in,
                              void* d_out, int out_size, void* d_ws, size_t ws_size,
                              hipStream_t stream) {
    const float* emb    = (const float*)d_in[0];   // [256][512]
    const int*   labels = (const int*)d_in[1];     // [256]
    const float* fc     = (const float*)d_in[2];   // [81920][512]
    float* out = (float*)d_out;

    char* ws = (char*)d_ws;
    bf16*  embb      = (bf16*)ws;                        //   262144 B
    float* hT        = (float*)(ws + 262144);            //  8388608 B
    float* gram_part = (float*)(ws + 8650752);           //     8192 B
    float* part_m    = (float*)(ws + 8658944);           //   131072 B
    float* part_s    = (float*)(ws + 8790016);           //   131072 B

    conv_kernel<<<64, 256, 0, stream>>>(emb, embb);
    fused_kernel<<<256, 512, 0, stream>>>(fc, embb, hT, gram_part);
    ce_kernel<<<128, 256, 0, stream>>>(hT, labels, part_m, part_s);
    final_kernel<<<1, 256, 0, stream>>>(part_m, part_s, hT, labels, gram_part, out);
}